// Round 6
// baseline (57.006 us; speedup 1.0000x reference)
//
#include <hip/hip_runtime.h>

// EdgeConsistencyLoss: mean((|∇edit| - |∇src|)^2) with Sobel 3x3, SAME zero pad.
// [B=16, C=8, H=512, W=512] fp32 -> 128 independent 512x512 images.
//
// R1: occupancy alone didn't help; halo bytes hurt. Time ~ HBM bytes.
// R2: sw-pipeline depth-1: 52.5us.
// R3: 64-VGPR cap -> spill (WRITE 174MB) -> 123us. Reverted.
// R4: shfl halos + seam regs + depth-2 prefetch: 50.9us, 64 VGPR, FETCH 138.8MB
//     (minimal). VALU ~52% busy at graph time -> instruction-count bound.
// R5: packed-fp32 math via ext_vector_type(2) (v_pk_* dual fp32) + single-sqrt
//     identity (ee-es)^2 = S + E - 2*sqrt(S*E). Memory structure unchanged.

typedef float v2f __attribute__((ext_vector_type(2)));

#define EPS 1e-8f

constexpr int W_DIM  = 512;
constexpr int H_DIM  = 512;
constexpr int NIMG   = 128;           // B*C
constexpr int ROWS   = 32;            // rows per block chunk (multiple of 4)
constexpr int CHUNKS = H_DIM / ROWS;  // 16
constexpr int TPB    = 128;           // 2 waves; block covers full 512-px width
constexpr int NBLK   = NIMG * CHUNKS; // 2048
constexpr double TOTAL_ELEMS = 33554432.0; // 16*8*512*512

struct RowBuf { float4 s, e; float ss, es; };

__global__ __launch_bounds__(TPB) void edge_loss_stage1(
    const float* __restrict__ src, const float* __restrict__ edt,
    float* __restrict__ partial)
{
    const int blk  = blockIdx.x;
    const int img  = blk / CHUNKS;
    const int r0   = (blk % CHUNKS) * ROWS;
    const int wv   = threadIdx.x >> 6;
    const int lane = threadIdx.x & 63;
    const int c0   = threadIdx.x * 4;   // wave0: cols 0..255, wave1: 256..511

    const float* simg = src + (size_t)img * (H_DIM * W_DIM);
    const float* eimg = edt + (size_t)img * (H_DIM * W_DIM);

    // Wave-seam: wave0 lane63 needs col 256; wave1 lane0 needs col 255.
    // Image edges (col -1, col 512) are zero-pad; seam reg stays 0 there.
    const bool seam_active = (wv == 0) ? (lane == 63) : (lane == 0);
    const int  seamcol     = (wv == 0) ? 256 : 255;

    // Streaming Sobel state per column-pair j (v2f = 2 columns):
    //   a(h) = x[h,w+1]-x[h,w-1];  b(h) = x[h,w-1]+2x[h,w]+x[h,w+1]
    //   gx(h-1) = P0 + a(h);  gy(h-1) = b(h) - Q0
    //   P0' = P1 + 2a(h); P1' = a(h); Q0' = Q1; Q1' = b(h)
    v2f sP0[2], sP1[2], sQ0[2], sQ1[2];
    v2f eP0[2], eP1[2], eQ0[2], eQ1[2];
    v2f accv; accv.x = 0.f; accv.y = 0.f;

    auto issue = [&](int h, RowBuf& rb) {
        int hc = h < 0 ? 0 : (h >= H_DIM ? H_DIM - 1 : h);
        const float* srow = simg + (size_t)hc * W_DIM;
        const float* erow = eimg + (size_t)hc * W_DIM;
        rb.s = *reinterpret_cast<const float4*>(srow + c0);
        rb.e = *reinterpret_cast<const float4*>(erow + c0);
        rb.ss = 0.f; rb.es = 0.f;
        if (seam_active) { rb.ss = srow[seamcol]; rb.es = erow[seamcol]; }
    };

    // Row horizontal pass: a (gx part) and b (gy part) for both tensors,
    // 2 columns per v2f. Halos via shfl + seam regs.
    auto rowAB = [&](const RowBuf& rb,
                     v2f& sa0, v2f& sa1, v2f& sb0, v2f& sb1,
                     v2f& ea0, v2f& ea1, v2f& eb0, v2f& eb1) {
        float slT = __shfl_up(rb.s.w, 1);
        float srT = __shfl_down(rb.s.x, 1);
        float elT = __shfl_up(rb.e.w, 1);
        float erT = __shfl_down(rb.e.x, 1);
        float sl = (lane == 0)  ? rb.ss : slT;   // wave0 lane0: 0 (image edge)
        float sr = (lane == 63) ? rb.ss : srT;   // wave1 lane63: 0
        float el = (lane == 0)  ? rb.es : elT;
        float er = (lane == 63) ? rb.es : erT;

        v2f L01, L23, L45, M12, M34;
        L01.x = sl;      L01.y = rb.s.x;
        L23.x = rb.s.y;  L23.y = rb.s.z;
        L45.x = rb.s.w;  L45.y = sr;
        M12.x = rb.s.x;  M12.y = rb.s.y;
        M34.x = rb.s.z;  M34.y = rb.s.w;
        sa0 = L23 - L01;               sa1 = L45 - L23;
        sb0 = (L01 + L23) + 2.0f*M12;  sb1 = (L23 + L45) + 2.0f*M34;

        v2f K01, K23, K45, N12, N34;
        K01.x = el;      K01.y = rb.e.x;
        K23.x = rb.e.y;  K23.y = rb.e.z;
        K45.x = rb.e.w;  K45.y = er;
        N12.x = rb.e.x;  N12.y = rb.e.y;
        N34.x = rb.e.z;  N34.y = rb.e.w;
        ea0 = K23 - K01;               ea1 = K45 - K23;
        eb0 = (K01 + K23) + 2.0f*N12;  eb1 = (K23 + K45) + 2.0f*N34;
    };

    // Single-sqrt accumulate: (ee-es)^2 = S + E - 2*sqrt(S*E),
    // S = sgx^2+sgy^2+eps, E = egx^2+egy^2+eps.
    auto accum = [&](v2f S, v2f E) {
        v2f m = S * E;
        v2f r;
        r.x = __builtin_amdgcn_sqrtf(m.x);
        r.y = __builtin_amdgcn_sqrtf(m.y);
        accv += (S + E) - 2.0f*r;
    };

    // Consume raw row h: emit output row h-1, advance state.
    auto consume = [&](const RowBuf& rb, int h) {
        if (h < H_DIM) {                      // wave-uniform branch
            v2f sa0, sa1, sb0, sb1, ea0, ea1, eb0, eb1;
            rowAB(rb, sa0, sa1, sb0, sb1, ea0, ea1, eb0, eb1);

            v2f sgx0 = sP0[0] + sa0,  sgx1 = sP0[1] + sa1;
            v2f sgy0 = sb0 - sQ0[0],  sgy1 = sb1 - sQ0[1];
            sP0[0] = 2.0f*sa0 + sP1[0]; sP1[0] = sa0;
            sP0[1] = 2.0f*sa1 + sP1[1]; sP1[1] = sa1;
            sQ0[0] = sQ1[0]; sQ1[0] = sb0;
            sQ0[1] = sQ1[1]; sQ1[1] = sb1;

            v2f egx0 = eP0[0] + ea0,  egx1 = eP0[1] + ea1;
            v2f egy0 = eb0 - eQ0[0],  egy1 = eb1 - eQ0[1];
            eP0[0] = 2.0f*ea0 + eP1[0]; eP1[0] = ea0;
            eP0[1] = 2.0f*ea1 + eP1[1]; eP1[1] = ea1;
            eQ0[0] = eQ1[0]; eQ1[0] = eb0;
            eQ0[1] = eQ1[1]; eQ1[1] = eb1;

            v2f S0 = sgx0*sgx0 + sgy0*sgy0 + EPS;
            v2f S1 = sgx1*sgx1 + sgy1*sgy1 + EPS;
            v2f E0 = egx0*egx0 + egy0*egy0 + EPS;
            v2f E1 = egx1*egx1 + egy1*egy1 + EPS;
            accum(S0, E0);
            accum(S1, E1);
        } else {
            // Zero-pad row below image: a=b=0 -> gx=P0, gy=-Q0 (sign squared
            // away). This is always the final consume; no state update needed.
            v2f S0 = sP0[0]*sP0[0] + sQ0[0]*sQ0[0] + EPS;
            v2f S1 = sP0[1]*sP0[1] + sQ0[1]*sQ0[1] + EPS;
            v2f E0 = eP0[0]*eP0[0] + eQ0[0]*eQ0[0] + EPS;
            v2f E1 = eP0[1]*eP0[1] + eQ0[1]*eQ0[1] + EPS;
            accum(S0, E0);
            accum(S1, E1);
        }
    };

    // ---- Prologue: 4 rows in flight before first consume. ----
    RowBuf bA0, bA1, bB0, bB1;
    issue(r0 - 1, bA0);
    issue(r0,     bA1);
    issue(r0 + 1, bB0);
    issue(r0 + 2, bB1);

    if (r0 > 0) {          // row r0-1 exists: P0 = a, Q0 = b
        v2f sa0, sa1, sb0, sb1, ea0, ea1, eb0, eb1;
        rowAB(bA0, sa0, sa1, sb0, sb1, ea0, ea1, eb0, eb1);
        sP0[0] = sa0; sP0[1] = sa1; sQ0[0] = sb0; sQ0[1] = sb1;
        eP0[0] = ea0; eP0[1] = ea1; eQ0[0] = eb0; eQ0[1] = eb1;
    } else {
        v2f z; z.x = 0.f; z.y = 0.f;
        sP0[0]=z; sP0[1]=z; sQ0[0]=z; sQ0[1]=z;
        eP0[0]=z; eP0[1]=z; eQ0[0]=z; eQ0[1]=z;
    }
    {   // row r0: P0 += 2a, P1 = a, Q1 = b
        v2f sa0, sa1, sb0, sb1, ea0, ea1, eb0, eb1;
        rowAB(bA1, sa0, sa1, sb0, sb1, ea0, ea1, eb0, eb1);
        sP0[0] += 2.0f*sa0; sP1[0] = sa0; sQ1[0] = sb0;
        sP0[1] += 2.0f*sa1; sP1[1] = sa1; sQ1[1] = sb1;
        eP0[0] += 2.0f*ea0; eP1[0] = ea0; eQ1[0] = eb0;
        eP0[1] += 2.0f*ea1; eP1[1] = ea1; eQ1[1] = eb1;
    }

    // ---- Main loop: 4 rows per iteration, A/B pair rotation, depth ~2. ----
    int h = r0 + 1;
    #pragma unroll 1
    for (int k = 0; k < ROWS / 4; ++k, h += 4) {
        if (h + 2 <= r0 + ROWS) issue(h + 2, bA0);
        if (h + 3 <= r0 + ROWS) issue(h + 3, bA1);
        consume(bB0, h);
        consume(bB1, h + 1);
        if (h + 4 <= r0 + ROWS) issue(h + 4, bB0);
        if (h + 5 <= r0 + ROWS) issue(h + 5, bB1);
        consume(bA0, h + 2);
        consume(bA1, h + 3);
    }

    // ---- Reduction: wave shuffle, then LDS across the 2 waves. ----
    float acc = accv.x + accv.y;
    #pragma unroll
    for (int off = 32; off > 0; off >>= 1)
        acc += __shfl_down(acc, off);
    __shared__ float wsum[TPB / 64];
    if (lane == 0) wsum[wv] = acc;
    __syncthreads();
    if (threadIdx.x == 0) {
        float tot = 0.f;
        #pragma unroll
        for (int i = 0; i < TPB / 64; ++i) tot += wsum[i];
        partial[blk] = tot;
    }
}

__global__ __launch_bounds__(256) void edge_loss_stage2(
    const float* __restrict__ partial, float* __restrict__ out, int nparts)
{
    double acc = 0.0;
    for (int i = threadIdx.x; i < nparts; i += 256)
        acc += (double)partial[i];
    #pragma unroll
    for (int off = 32; off > 0; off >>= 1)
        acc += __shfl_down(acc, off);
    __shared__ double wsum[4];
    const int wid  = threadIdx.x >> 6;
    const int lane = threadIdx.x & 63;
    if (lane == 0) wsum[wid] = acc;
    __syncthreads();
    if (threadIdx.x == 0) {
        double t = 0.0;
        #pragma unroll
        for (int i = 0; i < 4; ++i) t += wsum[i];
        out[0] = (float)(t / TOTAL_ELEMS);
    }
}

extern "C" void kernel_launch(void* const* d_in, const int* in_sizes, int n_in,
                              void* d_out, int out_size, void* d_ws, size_t ws_size,
                              hipStream_t stream) {
    const float* src = (const float*)d_in[0];  // source_latent
    const float* edt = (const float*)d_in[1];  // edited_latent
    // d_in[2]/d_in[3] are the fixed Sobel kernels; baked into the math above
    // (flip-sign ambiguity is irrelevant under the magnitude).
    float* out     = (float*)d_out;
    float* partial = (float*)d_ws;             // NBLK floats = 8 KB, overwritten every call

    edge_loss_stage1<<<dim3(NBLK), dim3(TPB), 0, stream>>>(src, edt, partial);
    edge_loss_stage2<<<dim3(1), dim3(256), 0, stream>>>(partial, out, NBLK);
}